// Round 4
// baseline (562.137 us; speedup 1.0000x reference)
//
#include <hip/hip_runtime.h>
#include <math.h>

// CropRoi fused pipeline, round 4: K3 with LDS tap-box staging + 512-thread blocks.
// Inputs (setup_inputs order):
// 0 img (unused), 1 out1 [2,64,64,64,64], 2 comb2 [2,128,32,32,32], 3 inputs (unused),
// 4 proposals [64,7] int32, 5 w_up[64,128], 6 b_up[64], 7 g_up[64], 8 bt_up[64],
// 9 w_b2[64,128], 10 b_b2[64], 11 g_b2[64], 12 bt_b2[64]
// Output: [64,64,6,6,6] f32.

#define EPSV 1e-5f
#define NPROP 64

typedef __attribute__((ext_vector_type(8))) short bf16x8;
typedef __attribute__((ext_vector_type(4))) float f32x4;

// align_corners 2x upsample 12->24: pos = d*11/23 (mirrors JAX f32 arithmetic)
__device__ __forceinline__ void interp_idx(int d, int& i0, int& i1, float& w) {
    float pos = (float)(d * 11) / 23.0f;
    float f = floorf(pos);
    i0 = (int)f;
    i1 = min(i0 + 1, 11);
    w = pos - f;
}

__device__ __forceinline__ unsigned f2bf(float f) {
    union { float f; unsigned u; } v; v.f = f;
    unsigned r = v.u + 0x7fffu + ((v.u >> 16) & 1u);   // RNE
    return r >> 16;
}
__device__ __forceinline__ float bflo(unsigned u) { return __uint_as_float(u << 16); }
__device__ __forceinline__ float bfhi(unsigned u) { return __uint_as_float(u & 0xffff0000u); }

// 16B-slot XOR swizzle within a 256B (Xin) or 128B (Tap) row.
__device__ __forceinline__ int swz(int row) { return (((row & 7) ^ ((row >> 3) & 7)) << 4); }

// K1: y4s[p][site(12^3)][o(64)] = conv1x1(comb2 crop) — SITE-MAJOR output.
__global__ __launch_bounds__(256) void k1_conv1(
    const float* __restrict__ comb2, const int* __restrict__ props,
    const float* __restrict__ w_up, const float* __restrict__ b_up,
    float* __restrict__ y4s)
{
    __shared__ float wT[128 * 64];   // wT[c*64 + o]
    __shared__ float bL[64];
    const int p = blockIdx.y;
    const int tid = threadIdx.x;
    for (int i = tid; i < 8192; i += 256) {
        int c = i >> 6, o = i & 63;
        wT[i] = w_up[o * 128 + c];
    }
    if (tid < 64) bL[tid] = b_up[tid];
    __syncthreads();

    const int b  = props[p * 7 + 0];
    const int z0 = props[p * 7 + 1] >> 2;
    const int y0 = props[p * 7 + 2] >> 2;
    const int x0 = props[p * 7 + 3] >> 2;
    const int og = tid >> 6;       // 0..3 -> o in [og*16, og*16+16)
    const int sl = tid & 63;

    for (int it = 0; it < 3; ++it) {
        int site = blockIdx.x * 192 + it * 64 + sl;   // < 1728
        int z = site / 144, rem = site % 144;
        int y = rem / 12, x = rem % 12;
        const float* src = comb2 + ((((long)b * 128) * 32 + (z0 + z)) * 32 + (y0 + y)) * 32 + (x0 + x);

        float acc[16];
        #pragma unroll
        for (int j = 0; j < 16; ++j) acc[j] = bL[og * 16 + j];

        for (int c = 0; c < 128; ++c) {
            float v = src[c * 32768];
            const float4* wv = (const float4*)&wT[c * 64 + og * 16];
            float4 w0 = wv[0], w1 = wv[1], w2 = wv[2], w3 = wv[3];
            acc[0]  += v * w0.x; acc[1]  += v * w0.y; acc[2]  += v * w0.z; acc[3]  += v * w0.w;
            acc[4]  += v * w1.x; acc[5]  += v * w1.y; acc[6]  += v * w1.z; acc[7]  += v * w1.w;
            acc[8]  += v * w2.x; acc[9]  += v * w2.y; acc[10] += v * w2.z; acc[11] += v * w2.w;
            acc[12] += v * w3.x; acc[13] += v * w3.y; acc[14] += v * w3.z; acc[15] += v * w3.w;
        }
        float* dst = y4s + ((long)p * 1728 + site) * 64 + og * 16;
        #pragma unroll
        for (int j = 0; j < 16; j += 4)
            *(float4*)(dst + j) = make_float4(acc[j], acc[j+1], acc[j+2], acc[j+3]);
    }
}

// K2: per (p,c) stats of the upsampled (24^3) field -> affine a1,b1 for stage-1 IN.
__global__ __launch_bounds__(256) void k2_stats1(
    const float* __restrict__ y4s, const float* __restrict__ g_up,
    const float* __restrict__ bt_up, float* __restrict__ a1, float* __restrict__ b1)
{
    __shared__ float ch[1728];
    __shared__ float red[8];
    const int c = blockIdx.x, p = blockIdx.y;
    const int tid = threadIdx.x;
    const float* src = y4s + (long)p * 110592 + c;
    for (int i = tid; i < 1728; i += 256) ch[i] = src[(long)i * 64];
    __syncthreads();

    float sum = 0.f, sq = 0.f;
    for (int s = tid; s < 13824; s += 256) {
        int z = s / 576, rem = s % 576;
        int y = rem / 24, x = rem % 24;
        int iz0, iz1, iy0, iy1, ix0, ix1; float wz, wy, wx;
        interp_idx(z, iz0, iz1, wz);
        interp_idx(y, iy0, iy1, wy);
        interp_idx(x, ix0, ix1, wx);
        float v00 = ch[iz0*144 + iy0*12 + ix0] * (1.f - wx) + ch[iz0*144 + iy0*12 + ix1] * wx;
        float v01 = ch[iz0*144 + iy1*12 + ix0] * (1.f - wx) + ch[iz0*144 + iy1*12 + ix1] * wx;
        float v10 = ch[iz1*144 + iy0*12 + ix0] * (1.f - wx) + ch[iz1*144 + iy0*12 + ix1] * wx;
        float v11 = ch[iz1*144 + iy1*12 + ix0] * (1.f - wx) + ch[iz1*144 + iy1*12 + ix1] * wx;
        float v0 = v00 * (1.f - wy) + v01 * wy;
        float v1 = v10 * (1.f - wy) + v11 * wy;
        float u  = v0  * (1.f - wz) + v1  * wz;
        sum += u; sq += u * u;
    }
    #pragma unroll
    for (int m = 32; m >= 1; m >>= 1) { sum += __shfl_xor(sum, m); sq += __shfl_xor(sq, m); }
    if ((tid & 63) == 0) { red[(tid >> 6) * 2] = sum; red[(tid >> 6) * 2 + 1] = sq; }
    __syncthreads();
    if (tid == 0) {
        sum = red[0] + red[2] + red[4] + red[6];
        sq  = red[1] + red[3] + red[5] + red[7];
        float mean = sum / 13824.0f;
        float var  = fmaxf(sq / 13824.0f - mean * mean, 0.0f);
        float r = rsqrtf(var + EPSV);
        float a = g_up[c] * r;
        a1[p * 64 + c] = a;
        b1[p * 64 + c] = bt_up[c] - mean * a;
    }
}

// K3: fused conv2 (bf16 MFMA) + stage-2 stats + per-window max/min.
// Grid (108, 64), 512 threads (8 waves). bx -> zw = bx/18, tw = bx%18; window pair is
// always (zw, yw=tw/3, xw=xwb..xwb+1) with xwb=(tw%3)*2. Stage the 4x4x6 low-res tap
// box into LDS (bf16, coalesced), then: waves 0-3 compute x1 (interp from LDS) while
// waves 4-7 pack the out1 crop. Phase B: wave w does o2-group (w&3), site-tiles (w>>2).
__global__ __launch_bounds__(512) void k3_conv2(
    const float* __restrict__ y4s, const float* __restrict__ out1,
    const int* __restrict__ props,
    const float* __restrict__ a1, const float* __restrict__ b1,
    const float* __restrict__ w_b2, const float* __restrict__ b_b2,
    float* __restrict__ s2sum, float* __restrict__ s2sq,
    float* __restrict__ wmaxg, float* __restrict__ wming)
{
    __shared__ __align__(16) char XinB[128 * 256];   // Xin[site][k] bf16, swizzled
    __shared__ __align__(16) char TapB[96 * 128];    // Tap[r][c64] bf16, swizzled
    __shared__ float a1L[64], b1L[64];

    const int bx = blockIdx.x, p = blockIdx.y;
    const int zw = bx / 18, tw = bx % 18;
    const int yw = tw / 3, xwb = (tw % 3) * 2;
    const int tid = threadIdx.x;
    const int w = tid >> 6, l = tid & 63;

    if (tid < 64) { a1L[tid] = a1[p * 64 + tid]; b1L[tid] = b1[p * 64 + tid]; }

    const int bidx = props[p * 7 + 0];
    const int z2 = props[p * 7 + 1] >> 1;
    const int y2 = props[p * 7 + 2] >> 1;
    const int x2 = props[p * 7 + 3] >> 1;
    const float* y4sp = y4s + (long)p * 110592;

    const int izb = (44 * zw) / 23;
    const int iyb = (44 * yw) / 23;
    const int ixb = (44 * xwb) / 23;

    // ---- stage the 4z x 4y x 6x tap box (96 rows x 64ch) as bf16, coalesced ----
    {
        const int l16 = tid & 15;
        for (int r = tid >> 4; r < 96; r += 32) {
            int gz = min(izb + r / 24, 11);
            int gy = min(iyb + (r / 6) % 4, 11);
            int gx = min(ixb + r % 6, 11);
            const float* src = y4sp + (gz * 144 + gy * 12 + gx) * 64 + l16 * 4;
            float4 v = *(const float4*)src;
            unsigned lo = f2bf(v.x) | (f2bf(v.y) << 16);
            unsigned hi = f2bf(v.z) | (f2bf(v.w) << 16);
            *(uint2*)(TapB + r * 128 + ((l16 * 8) ^ swz(r))) = make_uint2(lo, hi);
        }
    }

    // ---- Phase-B A-fragments (weights) from global, bf16 ----
    const int o2g = w & 3, sh = w >> 2;
    const int g = l >> 4;
    const int o2a = o2g * 16 + (l & 15);
    bf16x8 afr[4];
    #pragma unroll
    for (int kk = 0; kk < 4; ++kk) {
        const float* wp = w_b2 + o2a * 128 + kk * 32 + g * 8;
        #pragma unroll
        for (int j = 0; j < 8; ++j) afr[kk][j] = (short)f2bf(wp[j]);
    }
    float bb[4];
    #pragma unroll
    for (int j = 0; j < 4; ++j) bb[j] = b_b2[o2g * 16 + g * 4 + j];

    __syncthreads();   // tap box + a1L/b1L ready

    // ================= Phase A: fill Xin =================
    if (tid < 256) {
        // x1 half: site = tid&127, channel-half kh; interp 8 taps from LDS tap box
        const int site = tid & 127, kh = tid >> 7;
        const int wh = site >> 6, widx = site & 63;
        const int zl = widx >> 4, yl = (widx >> 2) & 3, xl = widx & 3;
        const int zg = zw * 4 + zl, yg = yw * 4 + yl, xg = (xwb + wh) * 4 + xl;
        int iz0, iz1, iy0, iy1, ix0, ix1; float wz, wy, wx;
        interp_idx(zg, iz0, iz1, wz);
        interp_idx(yg, iy0, iy1, wy);
        interp_idx(xg, ix0, ix1, wx);
        const int lz0 = iz0 - izb, lz1 = iz1 - izb;
        const int ly0 = iy0 - iyb, ly1 = iy1 - iyb;
        const int lx0 = ix0 - ixb, lx1 = ix1 - ixb;
        int tr[8] = { lz0*24+ly0*6+lx0, lz0*24+ly0*6+lx1, lz0*24+ly1*6+lx0, lz0*24+ly1*6+lx1,
                      lz1*24+ly0*6+lx0, lz1*24+ly0*6+lx1, lz1*24+ly1*6+lx0, lz1*24+ly1*6+lx1 };
        float wz0 = 1.f - wz, wy0 = 1.f - wy, wx0 = 1.f - wx;
        float tw8[8] = { wz0*wy0*wx0, wz0*wy0*wx, wz0*wy*wx0, wz0*wy*wx,
                         wz*wy0*wx0,  wz*wy0*wx,  wz*wy*wx0,  wz*wy*wx };
        const int sw = swz(site);
        const int rowOff = site << 8;
        #pragma unroll
        for (int j = 0; j < 4; ++j) {
            const int c0 = kh * 32 + j * 8;
            float u[8] = {0,0,0,0,0,0,0,0};
            #pragma unroll
            for (int t = 0; t < 8; ++t) {
                const int r = tr[t];
                uint4 tv = *(const uint4*)(TapB + r * 128 + ((c0 * 2) ^ swz(r)));
                float wt = tw8[t];
                u[0] += wt * bflo(tv.x); u[1] += wt * bfhi(tv.x);
                u[2] += wt * bflo(tv.y); u[3] += wt * bfhi(tv.y);
                u[4] += wt * bflo(tv.z); u[5] += wt * bfhi(tv.z);
                u[6] += wt * bflo(tv.w); u[7] += wt * bfhi(tv.w);
            }
            unsigned pk[4];
            #pragma unroll
            for (int q = 0; q < 8; q += 2) {
                float va = fmaxf(a1L[c0+q]   * u[q]   + b1L[c0+q],   0.0f);
                float vb = fmaxf(a1L[c0+q+1] * u[q+1] + b1L[c0+q+1], 0.0f);
                pk[q >> 1] = f2bf(va) | (f2bf(vb) << 16);
            }
            *(uint4*)(XinB + rowOff + ((c0 * 2) ^ sw)) = make_uint4(pk[0], pk[1], pk[2], pk[3]);
        }
    } else {
        // out1 half: thread -> (window-row rq, 8-channel group cg); float2 x-loads
        const int t2 = tid & 255;
        const int rq = t2 & 31, cg = t2 >> 5;
        const int wh = rq >> 4, zl = (rq >> 2) & 3, yl = rq & 3;
        const int zg = zw * 4 + zl, yg = yw * 4 + yl, xg0 = (xwb + wh) * 4;
        const float* o1p = out1 + ((long)bidx * 64 + cg * 8) * 262144
                         + (long)(z2 + zg) * 4096 + (y2 + yg) * 64 + (x2 + xg0);
        float vx[8][4];
        #pragma unroll
        for (int c = 0; c < 8; ++c) {
            float2 va = *(const float2*)(o1p + (long)c * 262144);
            float2 vb = *(const float2*)(o1p + (long)c * 262144 + 2);
            vx[c][0] = va.x; vx[c][1] = va.y; vx[c][2] = vb.x; vx[c][3] = vb.y;
        }
        #pragma unroll
        for (int xl = 0; xl < 4; ++xl) {
            int site = wh * 64 + zl * 16 + yl * 4 + xl;
            unsigned pk[4];
            #pragma unroll
            for (int j = 0; j < 4; ++j)
                pk[j] = f2bf(vx[2*j][xl]) | (f2bf(vx[2*j+1][xl]) << 16);
            *(uint4*)(XinB + (site << 8) + ((128 + cg * 16) ^ swz(site))) = make_uint4(pk[0], pk[1], pk[2], pk[3]);
        }
    }
    __syncthreads();

    // ================= Phase B: MFMA; wave w -> o2-group (w&3), site-tiles sh*4.. =================
    float lS[4] = {0,0,0,0}, lQ[4] = {0,0,0,0};
    float vmx[4], vmn[4];
    #pragma unroll
    for (int q = 0; q < 4; ++q) { vmx[q] = -3.402823466e38f; vmn[q] = 3.402823466e38f; }

    #pragma unroll
    for (int i = 0; i < 4; ++i) {
        const int st = sh * 4 + i;
        const int srow = st * 16 + (l & 15);
        const int sOff = srow << 8;
        const int ssw = swz(srow);
        bf16x8 bfr[4];
        #pragma unroll
        for (int kk = 0; kk < 4; ++kk) {
            int kbyte = kk * 64 + g * 16;
            bfr[kk] = *(const bf16x8*)(XinB + sOff + (kbyte ^ ssw));
        }
        f32x4 acc = {0.f, 0.f, 0.f, 0.f};
        #pragma unroll
        for (int kk = 0; kk < 4; ++kk)
            acc = __builtin_amdgcn_mfma_f32_16x16x32_bf16(afr[kk], bfr[kk], acc, 0, 0, 0);

        #pragma unroll
        for (int j = 0; j < 4; ++j) {
            float v = acc[j] + bb[j];
            lS[j] += v; lQ[j] += v * v;
            vmx[j] = fmaxf(vmx[j], v);
            vmn[j] = fminf(vmn[j], v);
        }
    }

    // window reduce across the 16 site-columns (window = this wave's 4 site-tiles)
    #pragma unroll
    for (int j = 0; j < 4; ++j) {
        float mx = vmx[j], mn = vmn[j];
        #pragma unroll
        for (int m = 1; m <= 8; m <<= 1) {
            mx = fmaxf(mx, __shfl_xor(mx, m));
            mn = fminf(mn, __shfl_xor(mn, m));
        }
        vmx[j] = mx; vmn[j] = mn;
    }
    if ((l & 15) == 0) {
        int win = tw * 2 + sh;
        #pragma unroll
        for (int j = 0; j < 4; ++j) {
            int o2d = o2g * 16 + g * 4 + j;
            long idx = ((long)(p * 64 + o2d) * 6 + zw) * 36 + win;
            wmaxg[idx] = vmx[j];
            wming[idx] = vmn[j];
        }
    }

    // ---- stats reduction across the 16 site-columns, then atomics ----
    #pragma unroll
    for (int j = 0; j < 4; ++j) {
        #pragma unroll
        for (int m = 1; m <= 8; m <<= 1) {
            lS[j] += __shfl_xor(lS[j], m);
            lQ[j] += __shfl_xor(lQ[j], m);
        }
    }
    if ((l & 15) == 0) {
        #pragma unroll
        for (int j = 0; j < 4; ++j) {
            int o2d = o2g * 16 + g * 4 + j;
            atomicAdd(&s2sum[p * 64 + o2d], lS[j]);
            atomicAdd(&s2sq [p * 64 + o2d], lQ[j]);
        }
    }
}

// K4: finalize: apply stage-2 IN affine to window max (or min if negative scale), relu, write.
__global__ __launch_bounds__(256) void k4_final(
    const float* __restrict__ s2sum, const float* __restrict__ s2sq,
    const float* __restrict__ g_b2, const float* __restrict__ bt_b2,
    const float* __restrict__ wmaxg, const float* __restrict__ wming,
    float* __restrict__ outp)
{
    const int p = blockIdx.x;
    for (int idx = threadIdx.x; idx < 64 * 216; idx += 256) {
        int o2 = idx / 216, win = idx % 216;
        float s = s2sum[p * 64 + o2], q = s2sq[p * 64 + o2];
        float mean = s / 13824.0f;
        float var  = fmaxf(q / 13824.0f - mean * mean, 0.0f);
        float r = rsqrtf(var + EPSV);
        float sc = g_b2[o2] * r;
        float tb = bt_b2[o2] - mean * sc;
        long fi = (long)(p * 64 + o2) * 216 + win;
        float v = (sc >= 0.f) ? sc * wmaxg[fi] + tb : sc * wming[fi] + tb;
        outp[fi] = fmaxf(v, 0.0f);
    }
}

extern "C" void kernel_launch(void* const* d_in, const int* in_sizes, int n_in,
                              void* d_out, int out_size, void* d_ws, size_t ws_size,
                              hipStream_t stream)
{
    const float* out1  = (const float*)d_in[1];
    const float* comb2 = (const float*)d_in[2];
    const int*   props = (const int*)d_in[4];
    const float* w_up  = (const float*)d_in[5];
    const float* b_up  = (const float*)d_in[6];
    const float* g_up  = (const float*)d_in[7];
    const float* bt_up = (const float*)d_in[8];
    const float* w_b2  = (const float*)d_in[9];
    const float* b_b2  = (const float*)d_in[10];
    const float* g_b2  = (const float*)d_in[11];
    const float* bt_b2 = (const float*)d_in[12];
    float* outp = (float*)d_out;

    float* ws    = (float*)d_ws;
    float* y4s   = ws;                      // 64*1728*64 = 7,077,888 floats (site-major)
    float* a1    = y4s + 7077888;           // 4096
    float* b1    = a1 + 4096;               // 4096
    float* s2sum = b1 + 4096;               // 4096 (zeroed each call)
    float* s2sq  = s2sum + 4096;            // 4096 (zeroed each call)
    float* wmaxg = s2sq + 4096;             // 64*64*216 = 884,736
    float* wming = wmaxg + 884736;          // 884,736
    // total ~33.9 MiB

    hipMemsetAsync(s2sum, 0, 2 * 4096 * sizeof(float), stream);

    k1_conv1<<<dim3(9, NPROP), 256, 0, stream>>>(comb2, props, w_up, b_up, y4s);
    k2_stats1<<<dim3(64, NPROP), 256, 0, stream>>>(y4s, g_up, bt_up, a1, b1);
    k3_conv2<<<dim3(108, NPROP), 512, 0, stream>>>(y4s, out1, props, a1, b1, w_b2, b_b2,
                                                   s2sum, s2sq, wmaxg, wming);
    k4_final<<<NPROP, 256, 0, stream>>>(s2sum, s2sq, g_b2, bt_b2, wmaxg, wming, outp);
}

// Round 5
// 382.211 us; speedup vs baseline: 1.4707x; 1.4707x over previous
//
#include <hip/hip_runtime.h>
#include <math.h>

// CropRoi fused pipeline, round 5: R3 chassis + channel-major coalesced staging + XCD pinning.
// Inputs (setup_inputs order):
// 0 img (unused), 1 out1 [2,64,64,64,64], 2 comb2 [2,128,32,32,32], 3 inputs (unused),
// 4 proposals [64,7] int32, 5 w_up[64,128], 6 b_up[64], 7 g_up[64], 8 bt_up[64],
// 9 w_b2[64,128], 10 b_b2[64], 11 g_b2[64], 12 bt_b2[64]
// Output: [64,64,6,6,6] f32.

#define EPSV 1e-5f
#define NPROP 64

typedef __attribute__((ext_vector_type(8))) short bf16x8;
typedef __attribute__((ext_vector_type(4))) float f32x4;

// align_corners 2x upsample 12->24: pos = d*11/23 (mirrors JAX f32 arithmetic)
__device__ __forceinline__ void interp_idx(int d, int& i0, int& i1, float& w) {
    float pos = (float)(d * 11) / 23.0f;
    float f = floorf(pos);
    i0 = (int)f;
    i1 = min(i0 + 1, 11);
    w = pos - f;
}

__device__ __forceinline__ unsigned f2bf(float f) {
    union { float f; unsigned u; } v; v.f = f;
    unsigned r = v.u + 0x7fffu + ((v.u >> 16) & 1u);   // RNE
    return r >> 16;
}

// 16B-slot XOR swizzle within a 128B half-row; bijective per 8-row stripe.
__device__ __forceinline__ int swz(int row) { return (((row & 7) ^ ((row >> 3) & 7)) << 4); }

// K1: y4s[p][site(12^3)][o(64)] = conv1x1(comb2 crop) — SITE-MAJOR output.
__global__ __launch_bounds__(256) void k1_conv1(
    const float* __restrict__ comb2, const int* __restrict__ props,
    const float* __restrict__ w_up, const float* __restrict__ b_up,
    float* __restrict__ y4s)
{
    __shared__ float wT[128 * 64];   // wT[c*64 + o]
    __shared__ float bL[64];
    const int p = blockIdx.y;
    const int tid = threadIdx.x;
    for (int i = tid; i < 8192; i += 256) {
        int c = i >> 6, o = i & 63;
        wT[i] = w_up[o * 128 + c];
    }
    if (tid < 64) bL[tid] = b_up[tid];
    __syncthreads();

    const int b  = props[p * 7 + 0];
    const int z0 = props[p * 7 + 1] >> 2;
    const int y0 = props[p * 7 + 2] >> 2;
    const int x0 = props[p * 7 + 3] >> 2;
    const int og = tid >> 6;       // 0..3 -> o in [og*16, og*16+16)
    const int sl = tid & 63;

    int site = blockIdx.x * 64 + sl;   // < 1728 (grid.x = 27)
    int z = site / 144, rem = site % 144;
    int y = rem / 12, x = rem % 12;
    const float* src = comb2 + ((((long)b * 128) * 32 + (z0 + z)) * 32 + (y0 + y)) * 32 + (x0 + x);

    float acc[16];
    #pragma unroll
    for (int j = 0; j < 16; ++j) acc[j] = bL[og * 16 + j];

    for (int c = 0; c < 128; ++c) {
        float v = src[c * 32768];
        const float4* wv = (const float4*)&wT[c * 64 + og * 16];
        float4 w0 = wv[0], w1 = wv[1], w2 = wv[2], w3 = wv[3];
        acc[0]  += v * w0.x; acc[1]  += v * w0.y; acc[2]  += v * w0.z; acc[3]  += v * w0.w;
        acc[4]  += v * w1.x; acc[5]  += v * w1.y; acc[6]  += v * w1.z; acc[7]  += v * w1.w;
        acc[8]  += v * w2.x; acc[9]  += v * w2.y; acc[10] += v * w2.z; acc[11] += v * w2.w;
        acc[12] += v * w3.x; acc[13] += v * w3.y; acc[14] += v * w3.z; acc[15] += v * w3.w;
    }
    float* dst = y4s + ((long)p * 1728 + site) * 64 + og * 16;
    #pragma unroll
    for (int j = 0; j < 16; j += 4)
        *(float4*)(dst + j) = make_float4(acc[j], acc[j+1], acc[j+2], acc[j+3]);
}

// K2: per (p,c) stats of the upsampled (24^3) field -> affine a1,b1 for stage-1 IN.
// 1-D grid, XCD-pinned: all blocks of proposal p land on XCD p&7.
__global__ __launch_bounds__(256) void k2_stats1(
    const float* __restrict__ y4s, const float* __restrict__ g_up,
    const float* __restrict__ bt_up, float* __restrict__ a1, float* __restrict__ b1)
{
    __shared__ float ch[1728];
    __shared__ float red[8];
    const int n = blockIdx.x;
    const int k = n >> 3, r = n & 7;
    const int p = r + 8 * (k / 64);
    const int c = k % 64;
    const int tid = threadIdx.x;
    const float* src = y4s + (long)p * 110592 + c;
    for (int i = tid; i < 1728; i += 256) ch[i] = src[(long)i * 64];
    __syncthreads();

    float sum = 0.f, sq = 0.f;
    for (int s = tid; s < 13824; s += 256) {
        int z = s / 576, rem = s % 576;
        int y = rem / 24, x = rem % 24;
        int iz0, iz1, iy0, iy1, ix0, ix1; float wz, wy, wx;
        interp_idx(z, iz0, iz1, wz);
        interp_idx(y, iy0, iy1, wy);
        interp_idx(x, ix0, ix1, wx);
        float v00 = ch[iz0*144 + iy0*12 + ix0] * (1.f - wx) + ch[iz0*144 + iy0*12 + ix1] * wx;
        float v01 = ch[iz0*144 + iy1*12 + ix0] * (1.f - wx) + ch[iz0*144 + iy1*12 + ix1] * wx;
        float v10 = ch[iz1*144 + iy0*12 + ix0] * (1.f - wx) + ch[iz1*144 + iy0*12 + ix1] * wx;
        float v11 = ch[iz1*144 + iy1*12 + ix0] * (1.f - wx) + ch[iz1*144 + iy1*12 + ix1] * wx;
        float v0 = v00 * (1.f - wy) + v01 * wy;
        float v1 = v10 * (1.f - wy) + v11 * wy;
        float u  = v0  * (1.f - wz) + v1  * wz;
        sum += u; sq += u * u;
    }
    #pragma unroll
    for (int m = 32; m >= 1; m >>= 1) { sum += __shfl_xor(sum, m); sq += __shfl_xor(sq, m); }
    if ((tid & 63) == 0) { red[(tid >> 6) * 2] = sum; red[(tid >> 6) * 2 + 1] = sq; }
    __syncthreads();
    if (tid == 0) {
        sum = red[0] + red[2] + red[4] + red[6];
        sq  = red[1] + red[3] + red[5] + red[7];
        float mean = sum / 13824.0f;
        float var  = fmaxf(sq / 13824.0f - mean * mean, 0.0f);
        float rr = rsqrtf(var + EPSV);
        float a = g_up[c] * rr;
        a1[p * 64 + c] = a;
        b1[p * 64 + c] = bt_up[c] - mean * a;
    }
}

// K3: fused conv2 (bf16 MFMA) + stage-2 stats + per-window max/min.
// 1-D grid 6912, XCD-pinned by p. Per block: one 128-site tile (window pair at zw,yw,xwb..+1).
// 256 threads. Phase A1: x1 staged CHANNEL-MAJOR (16 lanes = 16 float4-channel-quads of one
// site) -> coalesced 256B tap reads, L1-resident tap box. Phase A2: out1 crop float2x2.
// Phase B: R3's verified MFMA/pool/stats, with the stripe-XOR swizzle.
__global__ __launch_bounds__(256) void k3_conv2(
    const float* __restrict__ y4s, const float* __restrict__ out1,
    const int* __restrict__ props,
    const float* __restrict__ a1, const float* __restrict__ b1,
    const float* __restrict__ w_b2, const float* __restrict__ b_b2,
    float* __restrict__ s2sum, float* __restrict__ s2sq,
    float* __restrict__ wmaxg, float* __restrict__ wming)
{
    __shared__ __align__(16) char XinB[128 * 256];   // Xin[site][k] bf16, swizzled
    __shared__ __align__(16) float a1L[64];
    __shared__ __align__(16) float b1L[64];

    const int n = blockIdx.x;
    const int kb = n >> 3, rb = n & 7;
    const int p = rb + 8 * (kb / 108);
    const int bx = kb % 108;
    const int zw = bx / 18, tw = bx % 18;
    const int yw = tw / 3, xwb = (tw % 3) * 2;
    const int tid = threadIdx.x;
    const int w = tid >> 6, l = tid & 63;

    if (tid < 64) { a1L[tid] = a1[p * 64 + tid]; b1L[tid] = b1[p * 64 + tid]; }

    const int bidx = props[p * 7 + 0];
    const int z2 = props[p * 7 + 1] >> 1;
    const int y2 = props[p * 7 + 2] >> 1;
    const int x2 = props[p * 7 + 3] >> 1;
    const float* y4sp = y4s + (long)p * 110592;

    // ---- Phase-B A-fragments (weights) from global, bf16 ----
    const int g = l >> 4;                 // k-group
    const int o2a = (w << 4) + (l & 15);  // A-operand row
    bf16x8 afr[4];
    #pragma unroll
    for (int kk = 0; kk < 4; ++kk) {
        const float* wp = w_b2 + o2a * 128 + kk * 32 + g * 8;
        #pragma unroll
        for (int j = 0; j < 8; ++j) afr[kk][j] = (short)f2bf(wp[j]);
    }
    float bb[4];
    #pragma unroll
    for (int j = 0; j < 4; ++j) bb[j] = b_b2[(w << 4) + g * 4 + j];

    __syncthreads();   // a1L/b1L ready

    // ================= Phase A1: x1, channel-major =================
    {
        const int chq = l & 15;           // channel quad: c0 = chq*4
        const int ssub = l >> 2 >> 2;     // l>>4: 0..3
        const float* base = y4sp + chq * 4;
        const float4 av = *(const float4*)&a1L[chq * 4];
        const float4 bv = *(const float4*)&b1L[chq * 4];
        #pragma unroll
        for (int it = 0; it < 8; ++it) {
            const int site = it * 16 + w * 4 + ssub;
            const int wh = site >> 6, widx = site & 63;
            const int zl = widx >> 4, yl = (widx >> 2) & 3, xl = widx & 3;
            const int zg = zw * 4 + zl, yg = yw * 4 + yl, xg = (xwb + wh) * 4 + xl;
            int iz0, iz1, iy0, iy1, ix0, ix1; float wz, wy, wx;
            interp_idx(zg, iz0, iz1, wz);
            interp_idx(yg, iy0, iy1, wy);
            interp_idx(xg, ix0, ix1, wx);
            float wz0 = 1.f - wz, wy0 = 1.f - wy, wx0 = 1.f - wx;
            float tw8[8] = { wz0*wy0*wx0, wz0*wy0*wx, wz0*wy*wx0, wz0*wy*wx,
                             wz*wy0*wx0,  wz*wy0*wx,  wz*wy*wx0,  wz*wy*wx };
            int o8[8] = { (iz0*144+iy0*12+ix0)*64, (iz0*144+iy0*12+ix1)*64,
                          (iz0*144+iy1*12+ix0)*64, (iz0*144+iy1*12+ix1)*64,
                          (iz1*144+iy0*12+ix0)*64, (iz1*144+iy0*12+ix1)*64,
                          (iz1*144+iy1*12+ix0)*64, (iz1*144+iy1*12+ix1)*64 };
            float u0 = 0.f, u1 = 0.f, u2 = 0.f, u3 = 0.f;
            #pragma unroll
            for (int t = 0; t < 8; ++t) {
                float4 v = *(const float4*)(base + o8[t]);
                float wt = tw8[t];
                u0 += wt * v.x; u1 += wt * v.y; u2 += wt * v.z; u3 += wt * v.w;
            }
            float r0 = fmaxf(av.x * u0 + bv.x, 0.0f);
            float r1 = fmaxf(av.y * u1 + bv.y, 0.0f);
            float r2 = fmaxf(av.z * u2 + bv.z, 0.0f);
            float r3 = fmaxf(av.w * u3 + bv.w, 0.0f);
            unsigned lo = f2bf(r0) | (f2bf(r1) << 16);
            unsigned hi = f2bf(r2) | (f2bf(r3) << 16);
            *(uint2*)(XinB + (site << 8) + ((chq * 8) ^ swz(site))) = make_uint2(lo, hi);
        }
    }

    // ================= Phase A2: out1 crop =================
    {
        const int rq = tid & 31, cg = tid >> 5;   // cg: channels cg*8..+8
        const int wh = rq >> 4, zl = (rq >> 2) & 3, yl = rq & 3;
        const int zg = zw * 4 + zl, yg = yw * 4 + yl, xg0 = (xwb + wh) * 4;
        const float* o1p = out1 + ((long)bidx * 64 + cg * 8) * 262144
                         + (long)(z2 + zg) * 4096 + (y2 + yg) * 64 + (x2 + xg0);
        float vx[8][4];
        #pragma unroll
        for (int c = 0; c < 8; ++c) {
            float2 va = *(const float2*)(o1p + (long)c * 262144);
            float2 vb = *(const float2*)(o1p + (long)c * 262144 + 2);
            vx[c][0] = va.x; vx[c][1] = va.y; vx[c][2] = vb.x; vx[c][3] = vb.y;
        }
        #pragma unroll
        for (int xl = 0; xl < 4; ++xl) {
            int site = wh * 64 + zl * 16 + yl * 4 + xl;
            unsigned pk[4];
            #pragma unroll
            for (int j = 0; j < 4; ++j)
                pk[j] = f2bf(vx[2*j][xl]) | (f2bf(vx[2*j+1][xl]) << 16);
            *(uint4*)(XinB + (site << 8) + ((128 + cg * 16) ^ swz(site))) = make_uint4(pk[0], pk[1], pk[2], pk[3]);
        }
    }
    __syncthreads();

    // ================= Phase B: MFMA over 8 site-tiles =================
    float lS[4] = {0,0,0,0}, lQ[4] = {0,0,0,0};
    float vmx[2][4], vmn[2][4];
    #pragma unroll
    for (int q = 0; q < 4; ++q) {
        vmx[0][q] = vmx[1][q] = -3.402823466e38f;
        vmn[0][q] = vmn[1][q] =  3.402823466e38f;
    }

    #pragma unroll
    for (int st = 0; st < 8; ++st) {
        const int srow = st * 16 + (l & 15);
        const int sOff = srow << 8;
        const int ssw = swz(srow);
        bf16x8 bfr[4];
        #pragma unroll
        for (int kk = 0; kk < 4; ++kk) {
            int kbyte = kk * 64 + g * 16;
            bfr[kk] = *(const bf16x8*)(XinB + sOff + (kbyte ^ ssw));
        }
        f32x4 acc = {0.f, 0.f, 0.f, 0.f};
        #pragma unroll
        for (int kk = 0; kk < 4; ++kk)
            acc = __builtin_amdgcn_mfma_f32_16x16x32_bf16(afr[kk], bfr[kk], acc, 0, 0, 0);

        const int wh = st >> 2;
        #pragma unroll
        for (int j = 0; j < 4; ++j) {
            float v = acc[j] + bb[j];
            lS[j] += v; lQ[j] += v * v;
            vmx[wh][j] = fmaxf(vmx[wh][j], v);
            vmn[wh][j] = fminf(vmn[wh][j], v);
        }
    }

    // window reduce across the 16 site-columns
    #pragma unroll
    for (int wh = 0; wh < 2; ++wh)
        #pragma unroll
        for (int j = 0; j < 4; ++j) {
            float mx = vmx[wh][j], mn = vmn[wh][j];
            #pragma unroll
            for (int m = 1; m <= 8; m <<= 1) {
                mx = fmaxf(mx, __shfl_xor(mx, m));
                mn = fminf(mn, __shfl_xor(mn, m));
            }
            vmx[wh][j] = mx; vmn[wh][j] = mn;
        }
    if ((l & 15) == 0) {
        #pragma unroll
        for (int wh = 0; wh < 2; ++wh) {
            int win = tw * 2 + wh;
            #pragma unroll
            for (int j = 0; j < 4; ++j) {
                int o2d = (w << 4) + g * 4 + j;
                long idx = ((long)(p * 64 + o2d) * 6 + zw) * 36 + win;
                wmaxg[idx] = vmx[wh][j];
                wming[idx] = vmn[wh][j];
            }
        }
    }

    // ---- stats reduction across the 16 site-columns, then atomics ----
    #pragma unroll
    for (int j = 0; j < 4; ++j) {
        #pragma unroll
        for (int m = 1; m <= 8; m <<= 1) {
            lS[j] += __shfl_xor(lS[j], m);
            lQ[j] += __shfl_xor(lQ[j], m);
        }
    }
    if ((l & 15) == 0) {
        #pragma unroll
        for (int j = 0; j < 4; ++j) {
            int o2d = (w << 4) + g * 4 + j;
            atomicAdd(&s2sum[p * 64 + o2d], lS[j]);
            atomicAdd(&s2sq [p * 64 + o2d], lQ[j]);
        }
    }
}

// K4: finalize: apply stage-2 IN affine to window max (or min if negative scale), relu, write.
__global__ __launch_bounds__(256) void k4_final(
    const float* __restrict__ s2sum, const float* __restrict__ s2sq,
    const float* __restrict__ g_b2, const float* __restrict__ bt_b2,
    const float* __restrict__ wmaxg, const float* __restrict__ wming,
    float* __restrict__ outp)
{
    const int p = blockIdx.x;
    for (int idx = threadIdx.x; idx < 64 * 216; idx += 256) {
        int o2 = idx / 216, win = idx % 216;
        float s = s2sum[p * 64 + o2], q = s2sq[p * 64 + o2];
        float mean = s / 13824.0f;
        float var  = fmaxf(q / 13824.0f - mean * mean, 0.0f);
        float r = rsqrtf(var + EPSV);
        float sc = g_b2[o2] * r;
        float tb = bt_b2[o2] - mean * sc;
        long fi = (long)(p * 64 + o2) * 216 + win;
        float v = (sc >= 0.f) ? sc * wmaxg[fi] + tb : sc * wming[fi] + tb;
        outp[fi] = fmaxf(v, 0.0f);
    }
}

extern "C" void kernel_launch(void* const* d_in, const int* in_sizes, int n_in,
                              void* d_out, int out_size, void* d_ws, size_t ws_size,
                              hipStream_t stream)
{
    const float* out1  = (const float*)d_in[1];
    const float* comb2 = (const float*)d_in[2];
    const int*   props = (const int*)d_in[4];
    const float* w_up  = (const float*)d_in[5];
    const float* b_up  = (const float*)d_in[6];
    const float* g_up  = (const float*)d_in[7];
    const float* bt_up = (const float*)d_in[8];
    const float* w_b2  = (const float*)d_in[9];
    const float* b_b2  = (const float*)d_in[10];
    const float* g_b2  = (const float*)d_in[11];
    const float* bt_b2 = (const float*)d_in[12];
    float* outp = (float*)d_out;

    float* ws    = (float*)d_ws;
    float* y4s   = ws;                      // 64*1728*64 = 7,077,888 floats (site-major)
    float* a1    = y4s + 7077888;           // 4096
    float* b1    = a1 + 4096;               // 4096
    float* s2sum = b1 + 4096;               // 4096 (zeroed each call)
    float* s2sq  = s2sum + 4096;            // 4096 (zeroed each call)
    float* wmaxg = s2sq + 4096;             // 64*64*216 = 884,736
    float* wming = wmaxg + 884736;          // 884,736
    // total ~33.9 MiB

    hipMemsetAsync(s2sum, 0, 2 * 4096 * sizeof(float), stream);

    k1_conv1<<<dim3(27, NPROP), 256, 0, stream>>>(comb2, props, w_up, b_up, y4s);
    k2_stats1<<<4096, 256, 0, stream>>>(y4s, g_up, bt_up, a1, b1);
    k3_conv2<<<6912, 256, 0, stream>>>(y4s, out1, props, a1, b1, w_b2, b_b2,
                                       s2sum, s2sq, wmaxg, wming);
    k4_final<<<NPROP, 256, 0, stream>>>(s2sum, s2sq, g_b2, bt_b2, wmaxg, wming, outp);
}

// Round 6
// 348.097 us; speedup vs baseline: 1.6149x; 1.0980x over previous
//
#include <hip/hip_runtime.h>
#include <math.h>

// CropRoi fused pipeline, round 6: kill division/cvt VALU fat via LDS tables + cvt_pk.
// Inputs (setup_inputs order):
// 0 img (unused), 1 out1 [2,64,64,64,64], 2 comb2 [2,128,32,32,32], 3 inputs (unused),
// 4 proposals [64,7] int32, 5 w_up[64,128], 6 b_up[64], 7 g_up[64], 8 bt_up[64],
// 9 w_b2[64,128], 10 b_b2[64], 11 g_b2[64], 12 bt_b2[64]
// Output: [64,64,6,6,6] f32.

#define EPSV 1e-5f
#define NPROP 64

typedef __attribute__((ext_vector_type(8))) short bf16x8;
typedef __attribute__((ext_vector_type(8))) unsigned short u16x8;
typedef __attribute__((ext_vector_type(4))) float f32x4;

// align_corners 2x upsample 12->24: pos = d*11/23 (mirrors JAX f32 arithmetic)
__device__ __forceinline__ void interp_idx(int d, int& i0, int& i1, float& w) {
    float pos = (float)(d * 11) / 23.0f;
    float f = floorf(pos);
    i0 = (int)f;
    i1 = min(i0 + 1, 11);
    w = pos - f;
}

__device__ __forceinline__ unsigned f2bf(float f) {
    union { float f; unsigned u; } v; v.f = f;
    unsigned r = v.u + 0x7fffu + ((v.u >> 16) & 1u);   // RNE
    return r >> 16;
}

// packed f32x2 -> bf16x2 (lo -> low16, hi -> high16), single HW instruction
__device__ __forceinline__ unsigned cvt_pk_bf16(float lo, float hi) {
    unsigned r;
    asm("v_cvt_pk_bf16_f32 %0, %1, %2" : "=v"(r) : "v"(lo), "v"(hi));
    return r;
}

// 16B-slot XOR swizzle within a 128B half-row; bijective per 8-row stripe.
__device__ __forceinline__ int swz(int row) { return (((row & 7) ^ ((row >> 3) & 7)) << 4); }

// K1: y4s[p][site(12^3)][o(64)] = conv1x1(comb2 crop) — SITE-MAJOR output.
__global__ __launch_bounds__(256) void k1_conv1(
    const float* __restrict__ comb2, const int* __restrict__ props,
    const float* __restrict__ w_up, const float* __restrict__ b_up,
    float* __restrict__ y4s)
{
    __shared__ float wT[128 * 64];   // wT[c*64 + o]
    __shared__ float bL[64];
    const int p = blockIdx.y;
    const int tid = threadIdx.x;
    for (int i = tid; i < 8192; i += 256) {
        int c = i >> 6, o = i & 63;
        wT[i] = w_up[o * 128 + c];
    }
    if (tid < 64) bL[tid] = b_up[tid];
    __syncthreads();

    const int b  = props[p * 7 + 0];
    const int z0 = props[p * 7 + 1] >> 2;
    const int y0 = props[p * 7 + 2] >> 2;
    const int x0 = props[p * 7 + 3] >> 2;
    const int og = tid >> 6;       // 0..3 -> o in [og*16, og*16+16)
    const int sl = tid & 63;

    int site = blockIdx.x * 64 + sl;   // < 1728 (grid.x = 27)
    int z = site / 144, rem = site % 144;
    int y = rem / 12, x = rem % 12;
    const float* src = comb2 + ((((long)b * 128) * 32 + (z0 + z)) * 32 + (y0 + y)) * 32 + (x0 + x);

    float acc[16];
    #pragma unroll
    for (int j = 0; j < 16; ++j) acc[j] = bL[og * 16 + j];

    for (int c = 0; c < 128; ++c) {
        float v = src[c * 32768];
        const float4* wv = (const float4*)&wT[c * 64 + og * 16];
        float4 w0 = wv[0], w1 = wv[1], w2 = wv[2], w3 = wv[3];
        acc[0]  += v * w0.x; acc[1]  += v * w0.y; acc[2]  += v * w0.z; acc[3]  += v * w0.w;
        acc[4]  += v * w1.x; acc[5]  += v * w1.y; acc[6]  += v * w1.z; acc[7]  += v * w1.w;
        acc[8]  += v * w2.x; acc[9]  += v * w2.y; acc[10] += v * w2.z; acc[11] += v * w2.w;
        acc[12] += v * w3.x; acc[13] += v * w3.y; acc[14] += v * w3.z; acc[15] += v * w3.w;
    }
    float* dst = y4s + ((long)p * 1728 + site) * 64 + og * 16;
    #pragma unroll
    for (int j = 0; j < 16; j += 4)
        *(float4*)(dst + j) = make_float4(acc[j], acc[j+1], acc[j+2], acc[j+3]);
}

// K2: per (p,c) stats of the upsampled (24^3) field -> affine a1,b1 for stage-1 IN.
// 1-D grid, XCD-pinned; per-axis interp table in LDS (no divisions in the loop).
__global__ __launch_bounds__(256) void k2_stats1(
    const float* __restrict__ y4s, const float* __restrict__ g_up,
    const float* __restrict__ bt_up, float* __restrict__ a1, float* __restrict__ b1)
{
    __shared__ float ch[1728];
    __shared__ float red[8];
    __shared__ int   tI[24];
    __shared__ float tW[24];
    const int n = blockIdx.x;
    const int k = n >> 3, r = n & 7;
    const int p = r + 8 * (k / 64);
    const int c = k % 64;
    const int tid = threadIdx.x;
    if (tid < 24) {
        int i0, i1; float w;
        interp_idx(tid, i0, i1, w);
        tI[tid] = i0; tW[tid] = w;
    }
    const float* src = y4s + (long)p * 110592 + c;
    for (int i = tid; i < 1728; i += 256) ch[i] = src[(long)i * 64];
    __syncthreads();

    float sum = 0.f, sq = 0.f;
    for (int s = tid; s < 13824; s += 256) {
        int z = s / 576, rem = s % 576;
        int y = rem / 24, x = rem % 24;
        int iz0 = tI[z], iy0 = tI[y], ix0 = tI[x];
        float wz = tW[z], wy = tW[y], wx = tW[x];
        int iz1 = min(iz0 + 1, 11), iy1 = min(iy0 + 1, 11), ix1 = min(ix0 + 1, 11);
        float v00 = ch[iz0*144 + iy0*12 + ix0] * (1.f - wx) + ch[iz0*144 + iy0*12 + ix1] * wx;
        float v01 = ch[iz0*144 + iy1*12 + ix0] * (1.f - wx) + ch[iz0*144 + iy1*12 + ix1] * wx;
        float v10 = ch[iz1*144 + iy0*12 + ix0] * (1.f - wx) + ch[iz1*144 + iy0*12 + ix1] * wx;
        float v11 = ch[iz1*144 + iy1*12 + ix0] * (1.f - wx) + ch[iz1*144 + iy1*12 + ix1] * wx;
        float v0 = v00 * (1.f - wy) + v01 * wy;
        float v1 = v10 * (1.f - wy) + v11 * wy;
        float u  = v0  * (1.f - wz) + v1  * wz;
        sum += u; sq += u * u;
    }
    #pragma unroll
    for (int m = 32; m >= 1; m >>= 1) { sum += __shfl_xor(sum, m); sq += __shfl_xor(sq, m); }
    if ((tid & 63) == 0) { red[(tid >> 6) * 2] = sum; red[(tid >> 6) * 2 + 1] = sq; }
    __syncthreads();
    if (tid == 0) {
        sum = red[0] + red[2] + red[4] + red[6];
        sq  = red[1] + red[3] + red[5] + red[7];
        float mean = sum / 13824.0f;
        float var  = fmaxf(sq / 13824.0f - mean * mean, 0.0f);
        float rr = rsqrtf(var + EPSV);
        float a = g_up[c] * rr;
        a1[p * 64 + c] = a;
        b1[p * 64 + c] = bt_up[c] - mean * a;
    }
}

// K3: fused conv2 (bf16 MFMA) + stage-2 stats + per-window max/min.
// 1-D grid 6912, XCD-pinned by p. Per block: one 128-site tile. 256 threads.
// Site tables (8 tap weights f32 + 8 tap site-indices u16 per site) built once in LDS;
// Phase A1 stages x1 channel-major with broadcast table reads; cvt_pk for bf16 packing.
__global__ __launch_bounds__(256) void k3_conv2(
    const float* __restrict__ y4s, const float* __restrict__ out1,
    const int* __restrict__ props,
    const float* __restrict__ a1, const float* __restrict__ b1,
    const float* __restrict__ w_b2, const float* __restrict__ b_b2,
    float* __restrict__ s2sum, float* __restrict__ s2sq,
    float* __restrict__ wmaxg, float* __restrict__ wming)
{
    __shared__ __align__(16) char XinB[128 * 256];   // Xin[site][k] bf16, swizzled
    __shared__ __align__(16) float Wt[128][8];       // tap weights per site
    __shared__ __align__(16) unsigned short Ot[128][8]; // tap site-indices (0..1727)
    __shared__ __align__(16) float a1L[64];
    __shared__ __align__(16) float b1L[64];

    const int n = blockIdx.x;
    const int kb = n >> 3, rb = n & 7;
    const int p = rb + 8 * (kb / 108);
    const int bx = kb % 108;
    const int zw = bx / 18, tw = bx % 18;
    const int yw = tw / 3, xwb = (tw % 3) * 2;
    const int tid = threadIdx.x;
    const int w = tid >> 6, l = tid & 63;

    if (tid < 64) { a1L[tid] = a1[p * 64 + tid]; b1L[tid] = b1[p * 64 + tid]; }

    // ---- build per-site tap tables (divisions happen ONCE here) ----
    if (tid < 128) {
        const int site = tid;
        const int wh = site >> 6, widx = site & 63;
        const int zl = widx >> 4, yl = (widx >> 2) & 3, xl = widx & 3;
        int iz0, iz1, iy0, iy1, ix0, ix1; float wz, wy, wx;
        interp_idx(zw * 4 + zl, iz0, iz1, wz);
        interp_idx(yw * 4 + yl, iy0, iy1, wy);
        interp_idx((xwb + wh) * 4 + xl, ix0, ix1, wx);
        float wz0 = 1.f - wz, wy0 = 1.f - wy, wx0 = 1.f - wx;
        Wt[site][0] = wz0*wy0*wx0; Wt[site][1] = wz0*wy0*wx;
        Wt[site][2] = wz0*wy*wx0;  Wt[site][3] = wz0*wy*wx;
        Wt[site][4] = wz*wy0*wx0;  Wt[site][5] = wz*wy0*wx;
        Wt[site][6] = wz*wy*wx0;   Wt[site][7] = wz*wy*wx;
        Ot[site][0] = (unsigned short)(iz0*144 + iy0*12 + ix0);
        Ot[site][1] = (unsigned short)(iz0*144 + iy0*12 + ix1);
        Ot[site][2] = (unsigned short)(iz0*144 + iy1*12 + ix0);
        Ot[site][3] = (unsigned short)(iz0*144 + iy1*12 + ix1);
        Ot[site][4] = (unsigned short)(iz1*144 + iy0*12 + ix0);
        Ot[site][5] = (unsigned short)(iz1*144 + iy0*12 + ix1);
        Ot[site][6] = (unsigned short)(iz1*144 + iy1*12 + ix0);
        Ot[site][7] = (unsigned short)(iz1*144 + iy1*12 + ix1);
    }

    const int bidx = props[p * 7 + 0];
    const int z2 = props[p * 7 + 1] >> 1;
    const int y2 = props[p * 7 + 2] >> 1;
    const int x2 = props[p * 7 + 3] >> 1;
    const float* y4sp = y4s + (long)p * 110592;

    // ---- Phase-B A-fragments (weights) from global, bf16 ----
    const int g = l >> 4;                 // k-group
    const int o2a = (w << 4) + (l & 15);  // A-operand row
    bf16x8 afr[4];
    #pragma unroll
    for (int kk = 0; kk < 4; ++kk) {
        const float* wp = w_b2 + o2a * 128 + kk * 32 + g * 8;
        #pragma unroll
        for (int j = 0; j < 8; ++j) afr[kk][j] = (short)f2bf(wp[j]);
    }
    float bb[4];
    #pragma unroll
    for (int j = 0; j < 4; ++j) bb[j] = b_b2[(w << 4) + g * 4 + j];

    __syncthreads();   // tables + a1L/b1L ready

    // ================= Phase A1: x1, channel-major, table-driven =================
    {
        const int chq = l & 15;           // channel quad: c0 = chq*4
        const int ssub = l >> 4;          // 0..3
        const float* base = y4sp + chq * 4;
        const float4 av = *(const float4*)&a1L[chq * 4];
        const float4 bv = *(const float4*)&b1L[chq * 4];
        #pragma unroll
        for (int it = 0; it < 8; ++it) {
            const int site = it * 16 + w * 4 + ssub;
            const float4 w0 = *(const float4*)&Wt[site][0];
            const float4 w1 = *(const float4*)&Wt[site][4];
            const u16x8 ov = *(const u16x8*)&Ot[site][0];
            float u0 = 0.f, u1 = 0.f, u2 = 0.f, u3 = 0.f;
            float wt8[8] = { w0.x, w0.y, w0.z, w0.w, w1.x, w1.y, w1.z, w1.w };
            #pragma unroll
            for (int t = 0; t < 8; ++t) {
                float4 v = *(const float4*)(base + (int)ov[t] * 64);
                float wt = wt8[t];
                u0 += wt * v.x; u1 += wt * v.y; u2 += wt * v.z; u3 += wt * v.w;
            }
            float r0 = fmaxf(av.x * u0 + bv.x, 0.0f);
            float r1 = fmaxf(av.y * u1 + bv.y, 0.0f);
            float r2 = fmaxf(av.z * u2 + bv.z, 0.0f);
            float r3 = fmaxf(av.w * u3 + bv.w, 0.0f);
            unsigned lo = cvt_pk_bf16(r0, r1);
            unsigned hi = cvt_pk_bf16(r2, r3);
            *(uint2*)(XinB + (site << 8) + ((chq * 8) ^ swz(site))) = make_uint2(lo, hi);
        }
    }

    // ================= Phase A2: out1 crop =================
    {
        const int rq = tid & 31, cg = tid >> 5;   // cg: channels cg*8..+8
        const int wh = rq >> 4, zl = (rq >> 2) & 3, yl = rq & 3;
        const int zg = zw * 4 + zl, yg = yw * 4 + yl, xg0 = (xwb + wh) * 4;
        const float* o1p = out1 + ((long)bidx * 64 + cg * 8) * 262144
                         + (long)(z2 + zg) * 4096 + (y2 + yg) * 64 + (x2 + xg0);
        float vx[8][4];
        #pragma unroll
        for (int c = 0; c < 8; ++c) {
            float2 va = *(const float2*)(o1p + (long)c * 262144);
            float2 vb = *(const float2*)(o1p + (long)c * 262144 + 2);
            vx[c][0] = va.x; vx[c][1] = va.y; vx[c][2] = vb.x; vx[c][3] = vb.y;
        }
        #pragma unroll
        for (int xl = 0; xl < 4; ++xl) {
            int site = wh * 64 + zl * 16 + yl * 4 + xl;
            unsigned pk[4];
            #pragma unroll
            for (int j = 0; j < 4; ++j)
                pk[j] = cvt_pk_bf16(vx[2*j][xl], vx[2*j+1][xl]);
            *(uint4*)(XinB + (site << 8) + ((128 + cg * 16) ^ swz(site))) = make_uint4(pk[0], pk[1], pk[2], pk[3]);
        }
    }
    __syncthreads();

    // ================= Phase B: MFMA over 8 site-tiles =================
    float lS[4] = {0,0,0,0}, lQ[4] = {0,0,0,0};
    float vmx[2][4], vmn[2][4];
    #pragma unroll
    for (int q = 0; q < 4; ++q) {
        vmx[0][q] = vmx[1][q] = -3.402823466e38f;
        vmn[0][q] = vmn[1][q] =  3.402823466e38f;
    }

    #pragma unroll
    for (int st = 0; st < 8; ++st) {
        const int srow = st * 16 + (l & 15);
        const int sOff = srow << 8;
        const int ssw = swz(srow);
        bf16x8 bfr[4];
        #pragma unroll
        for (int kk = 0; kk < 4; ++kk) {
            int kbyte = kk * 64 + g * 16;
            bfr[kk] = *(const bf16x8*)(XinB + sOff + (kbyte ^ ssw));
        }
        f32x4 acc = {0.f, 0.f, 0.f, 0.f};
        #pragma unroll
        for (int kk = 0; kk < 4; ++kk)
            acc = __builtin_amdgcn_mfma_f32_16x16x32_bf16(afr[kk], bfr[kk], acc, 0, 0, 0);

        const int wh = st >> 2;
        #pragma unroll
        for (int j = 0; j < 4; ++j) {
            float v = acc[j] + bb[j];
            lS[j] += v; lQ[j] += v * v;
            vmx[wh][j] = fmaxf(vmx[wh][j], v);
            vmn[wh][j] = fminf(vmn[wh][j], v);
        }
    }

    // window reduce across the 16 site-columns
    #pragma unroll
    for (int wh = 0; wh < 2; ++wh)
        #pragma unroll
        for (int j = 0; j < 4; ++j) {
            float mx = vmx[wh][j], mn = vmn[wh][j];
            #pragma unroll
            for (int m = 1; m <= 8; m <<= 1) {
                mx = fmaxf(mx, __shfl_xor(mx, m));
                mn = fminf(mn, __shfl_xor(mn, m));
            }
            vmx[wh][j] = mx; vmn[wh][j] = mn;
        }
    if ((l & 15) == 0) {
        #pragma unroll
        for (int wh = 0; wh < 2; ++wh) {
            int win = tw * 2 + wh;
            #pragma unroll
            for (int j = 0; j < 4; ++j) {
                int o2d = (w << 4) + g * 4 + j;
                long idx = ((long)(p * 64 + o2d) * 6 + zw) * 36 + win;
                wmaxg[idx] = vmx[wh][j];
                wming[idx] = vmn[wh][j];
            }
        }
    }

    // ---- stats reduction across the 16 site-columns, then atomics ----
    #pragma unroll
    for (int j = 0; j < 4; ++j) {
        #pragma unroll
        for (int m = 1; m <= 8; m <<= 1) {
            lS[j] += __shfl_xor(lS[j], m);
            lQ[j] += __shfl_xor(lQ[j], m);
        }
    }
    if ((l & 15) == 0) {
        #pragma unroll
        for (int j = 0; j < 4; ++j) {
            int o2d = (w << 4) + g * 4 + j;
            atomicAdd(&s2sum[p * 64 + o2d], lS[j]);
            atomicAdd(&s2sq [p * 64 + o2d], lQ[j]);
        }
    }
}

// K4: finalize: apply stage-2 IN affine to window max (or min if negative scale), relu, write.
__global__ __launch_bounds__(256) void k4_final(
    const float* __restrict__ s2sum, const float* __restrict__ s2sq,
    const float* __restrict__ g_b2, const float* __restrict__ bt_b2,
    const float* __restrict__ wmaxg, const float* __restrict__ wming,
    float* __restrict__ outp)
{
    const int p = blockIdx.x;
    for (int idx = threadIdx.x; idx < 64 * 216; idx += 256) {
        int o2 = idx / 216, win = idx % 216;
        float s = s2sum[p * 64 + o2], q = s2sq[p * 64 + o2];
        float mean = s / 13824.0f;
        float var  = fmaxf(q / 13824.0f - mean * mean, 0.0f);
        float r = rsqrtf(var + EPSV);
        float sc = g_b2[o2] * r;
        float tb = bt_b2[o2] - mean * sc;
        long fi = (long)(p * 64 + o2) * 216 + win;
        float v = (sc >= 0.f) ? sc * wmaxg[fi] + tb : sc * wming[fi] + tb;
        outp[fi] = fmaxf(v, 0.0f);
    }
}

extern "C" void kernel_launch(void* const* d_in, const int* in_sizes, int n_in,
                              void* d_out, int out_size, void* d_ws, size_t ws_size,
                              hipStream_t stream)
{
    const float* out1  = (const float*)d_in[1];
    const float* comb2 = (const float*)d_in[2];
    const int*   props = (const int*)d_in[4];
    const float* w_up  = (const float*)d_in[5];
    const float* b_up  = (const float*)d_in[6];
    const float* g_up  = (const float*)d_in[7];
    const float* bt_up = (const float*)d_in[8];
    const float* w_b2  = (const float*)d_in[9];
    const float* b_b2  = (const float*)d_in[10];
    const float* g_b2  = (const float*)d_in[11];
    const float* bt_b2 = (const float*)d_in[12];
    float* outp = (float*)d_out;

    float* ws    = (float*)d_ws;
    float* y4s   = ws;                      // 64*1728*64 = 7,077,888 floats (site-major)
    float* a1    = y4s + 7077888;           // 4096
    float* b1    = a1 + 4096;               // 4096
    float* s2sum = b1 + 4096;               // 4096 (zeroed each call)
    float* s2sq  = s2sum + 4096;            // 4096 (zeroed each call)
    float* wmaxg = s2sq + 4096;             // 64*64*216 = 884,736
    float* wming = wmaxg + 884736;          // 884,736
    // total ~33.9 MiB

    hipMemsetAsync(s2sum, 0, 2 * 4096 * sizeof(float), stream);

    k1_conv1<<<dim3(27, NPROP), 256, 0, stream>>>(comb2, props, w_up, b_up, y4s);
    k2_stats1<<<4096, 256, 0, stream>>>(y4s, g_up, bt_up, a1, b1);
    k3_conv2<<<6912, 256, 0, stream>>>(y4s, out1, props, a1, b1, w_b2, b_b2,
                                       s2sum, s2sq, wmaxg, wming);
    k4_final<<<NPROP, 256, 0, stream>>>(s2sum, s2sq, g_b2, bt_b2, wmaxg, wming, outp);
}

// Round 7
// 266.757 us; speedup vs baseline: 2.1073x; 1.3049x over previous
//
#include <hip/hip_runtime.h>
#include <math.h>

// CropRoi fused pipeline, round 7: bf16 y4s + MFMA k1 + register-batched taps + VGPR headroom.
// Inputs (setup_inputs order):
// 0 img (unused), 1 out1 [2,64,64,64,64], 2 comb2 [2,128,32,32,32], 3 inputs (unused),
// 4 proposals [64,7] int32, 5 w_up[64,128], 6 b_up[64], 7 g_up[64], 8 bt_up[64],
// 9 w_b2[64,128], 10 b_b2[64], 11 g_b2[64], 12 bt_b2[64]
// Output: [64,64,6,6,6] f32.

#define EPSV 1e-5f
#define NPROP 64

typedef __attribute__((ext_vector_type(8))) short bf16x8;
typedef __attribute__((ext_vector_type(8))) unsigned short u16x8;
typedef __attribute__((ext_vector_type(4))) float f32x4;

// align_corners 2x upsample 12->24: pos = d*11/23 (mirrors JAX f32 arithmetic)
__device__ __forceinline__ void interp_idx(int d, int& i0, int& i1, float& w) {
    float pos = (float)(d * 11) / 23.0f;
    float f = floorf(pos);
    i0 = (int)f;
    i1 = min(i0 + 1, 11);
    w = pos - f;
}

__device__ __forceinline__ unsigned f2bf(float f) {
    union { float f; unsigned u; } v; v.f = f;
    unsigned r = v.u + 0x7fffu + ((v.u >> 16) & 1u);   // RNE
    return r >> 16;
}

// packed f32x2 -> bf16x2 (lo -> low16, hi -> high16), single HW instruction
__device__ __forceinline__ unsigned cvt_pk_bf16(float lo, float hi) {
    unsigned r;
    asm("v_cvt_pk_bf16_f32 %0, %1, %2" : "=v"(r) : "v"(lo), "v"(hi));
    return r;
}
__device__ __forceinline__ float bflo(unsigned u) { return __uint_as_float(u << 16); }
__device__ __forceinline__ float bfhi(unsigned u) { return __uint_as_float(u & 0xffff0000u); }

// 16B-slot XOR swizzle within a 256B row; bijective per 8-row stripe.
__device__ __forceinline__ int swz(int row) { return (((row & 7) ^ ((row >> 3) & 7)) << 4); }

// K1: y4s[p][site(12^3)][o(64)] bf16 = conv1x1(comb2 crop), MFMA version.
// Grid 768 (XCD-pinned): block = (p, z-layer). Stage layer crop (144 sites x 128 ch)
// into swizzled LDS bf16 via coalesced float4 x-loads; 9 site-tiles of Phase-B MFMA.
__global__ __launch_bounds__(256, 4) void k1_conv1(
    const float* __restrict__ comb2, const int* __restrict__ props,
    const float* __restrict__ w_up, const float* __restrict__ b_up,
    unsigned short* __restrict__ y4s)
{
    __shared__ __align__(16) char XinB[144 * 256];   // [site144][c128] bf16, swizzled

    const int n = blockIdx.x;
    const int rb = n & 7, kb = n >> 3;         // XCD pin by p&7
    const int p = rb + 8 * (kb / 12);
    const int zl = kb % 12;
    const int tid = threadIdx.x;
    const int w = tid >> 6, l = tid & 63;

    const int b  = props[p * 7 + 0];
    const int z0 = props[p * 7 + 1] >> 2;
    const int y0 = props[p * 7 + 2] >> 2;
    const int x0 = props[p * 7 + 3] >> 2;

    // ---- A-fragments (w_up) + bias ----
    const int g = l >> 4;
    const int o2a = (w << 4) + (l & 15);
    bf16x8 afr[4];
    #pragma unroll
    for (int kk = 0; kk < 4; ++kk) {
        const float* wp = w_up + o2a * 128 + kk * 32 + g * 8;
        #pragma unroll
        for (int j = 0; j < 8; ++j) afr[kk][j] = (short)f2bf(wp[j]);
    }
    float bb[4];
    #pragma unroll
    for (int j = 0; j < 4; ++j) bb[j] = b_up[(w << 4) + g * 4 + j];

    // ---- stage comb2 layer: idx -> (c, y, xq); float4 along x ----
    const float* lbase = comb2 + ((((long)b * 128) * 32 + (z0 + zl)) * 32 + y0) * 32 + x0;
    #pragma unroll
    for (int k = 0; k < 18; ++k) {
        int idx = k * 256 + tid;            // < 4608 = 128*36
        int c = idx / 36, r = idx % 36;
        int y = r / 3, xq = r % 3;
        float4 v = *(const float4*)(lbase + (long)c * 32768 + y * 32 + xq * 4);
        unsigned r01 = cvt_pk_bf16(v.x, v.y);
        unsigned r23 = cvt_pk_bf16(v.z, v.w);
        int s0 = y * 12 + xq * 4;
        *(unsigned short*)(XinB + (s0 << 8)       + ((c * 2) ^ swz(s0)))     = (unsigned short)r01;
        *(unsigned short*)(XinB + ((s0 + 1) << 8) + ((c * 2) ^ swz(s0 + 1))) = (unsigned short)(r01 >> 16);
        *(unsigned short*)(XinB + ((s0 + 2) << 8) + ((c * 2) ^ swz(s0 + 2))) = (unsigned short)r23;
        *(unsigned short*)(XinB + ((s0 + 3) << 8) + ((c * 2) ^ swz(s0 + 3))) = (unsigned short)(r23 >> 16);
    }
    __syncthreads();

    // ---- Phase B: 9 site-tiles of 16; write bf16 y4s ----
    unsigned short* orow = y4s + (long)p * 110592 + zl * 144 * 64;
    #pragma unroll
    for (int st = 0; st < 9; ++st) {
        const int srow = st * 16 + (l & 15);
        const int sOff = srow << 8;
        const int ssw = swz(srow);
        bf16x8 bfr[4];
        #pragma unroll
        for (int kk = 0; kk < 4; ++kk) {
            int kbyte = kk * 64 + g * 16;
            bfr[kk] = *(const bf16x8*)(XinB + sOff + (kbyte ^ ssw));
        }
        f32x4 acc = {0.f, 0.f, 0.f, 0.f};
        #pragma unroll
        for (int kk = 0; kk < 4; ++kk)
            acc = __builtin_amdgcn_mfma_f32_16x16x32_bf16(afr[kk], bfr[kk], acc, 0, 0, 0);
        unsigned lo = cvt_pk_bf16(acc[0] + bb[0], acc[1] + bb[1]);
        unsigned hi = cvt_pk_bf16(acc[2] + bb[2], acc[3] + bb[3]);
        *(uint2*)(orow + srow * 64 + (w << 4) + g * 4) = make_uint2(lo, hi);
    }
}

// K2: per (p,c) stats of the upsampled (24^3) field -> affine a1,b1 for stage-1 IN.
// 1-D grid, XCD-pinned; per-axis interp table in LDS; bf16 y4s input.
__global__ __launch_bounds__(256) void k2_stats1(
    const unsigned short* __restrict__ y4s, const float* __restrict__ g_up,
    const float* __restrict__ bt_up, float* __restrict__ a1, float* __restrict__ b1)
{
    __shared__ float ch[1728];
    __shared__ float red[8];
    __shared__ int   tI[24];
    __shared__ float tW[24];
    const int n = blockIdx.x;
    const int k = n >> 3, r = n & 7;
    const int p = r + 8 * (k / 64);
    const int c = k % 64;
    const int tid = threadIdx.x;
    if (tid < 24) {
        int i0, i1; float w;
        interp_idx(tid, i0, i1, w);
        tI[tid] = i0; tW[tid] = w;
    }
    const unsigned short* src = y4s + (long)p * 110592 + c;
    for (int i = tid; i < 1728; i += 256)
        ch[i] = __uint_as_float((unsigned)src[(long)i * 64] << 16);
    __syncthreads();

    float sum = 0.f, sq = 0.f;
    for (int s = tid; s < 13824; s += 256) {
        int z = s / 576, rem = s % 576;
        int y = rem / 24, x = rem % 24;
        int iz0 = tI[z], iy0 = tI[y], ix0 = tI[x];
        float wz = tW[z], wy = tW[y], wx = tW[x];
        int iz1 = min(iz0 + 1, 11), iy1 = min(iy0 + 1, 11), ix1 = min(ix0 + 1, 11);
        float v00 = ch[iz0*144 + iy0*12 + ix0] * (1.f - wx) + ch[iz0*144 + iy0*12 + ix1] * wx;
        float v01 = ch[iz0*144 + iy1*12 + ix0] * (1.f - wx) + ch[iz0*144 + iy1*12 + ix1] * wx;
        float v10 = ch[iz1*144 + iy0*12 + ix0] * (1.f - wx) + ch[iz1*144 + iy0*12 + ix1] * wx;
        float v11 = ch[iz1*144 + iy1*12 + ix0] * (1.f - wx) + ch[iz1*144 + iy1*12 + ix1] * wx;
        float v0 = v00 * (1.f - wy) + v01 * wy;
        float v1 = v10 * (1.f - wy) + v11 * wy;
        float u  = v0  * (1.f - wz) + v1  * wz;
        sum += u; sq += u * u;
    }
    #pragma unroll
    for (int m = 32; m >= 1; m >>= 1) { sum += __shfl_xor(sum, m); sq += __shfl_xor(sq, m); }
    if ((tid & 63) == 0) { red[(tid >> 6) * 2] = sum; red[(tid >> 6) * 2 + 1] = sq; }
    __syncthreads();
    if (tid == 0) {
        sum = red[0] + red[2] + red[4] + red[6];
        sq  = red[1] + red[3] + red[5] + red[7];
        float mean = sum / 13824.0f;
        float var  = fmaxf(sq / 13824.0f - mean * mean, 0.0f);
        float rr = rsqrtf(var + EPSV);
        float a = g_up[c] * rr;
        a1[p * 64 + c] = a;
        b1[p * 64 + c] = bt_up[c] - mean * a;
    }
}

// K3: fused conv2 (bf16 MFMA) + stage-2 stats + per-window max/min.
// 1-D grid 6912, XCD-pinned by p. 256 threads, VGPR budget 128 (launch_bounds 256,4).
// A1: per-site tap tables in LDS; 8 taps loaded as a register batch (bf16 y4s rows),
// then unpacked+FMA'd. A2: out1 crop float2x2. Phase B unchanged.
__global__ __launch_bounds__(256, 4) void k3_conv2(
    const unsigned short* __restrict__ y4s, const float* __restrict__ out1,
    const int* __restrict__ props,
    const float* __restrict__ a1, const float* __restrict__ b1,
    const float* __restrict__ w_b2, const float* __restrict__ b_b2,
    float* __restrict__ s2sum, float* __restrict__ s2sq,
    float* __restrict__ wmaxg, float* __restrict__ wming)
{
    __shared__ __align__(16) char XinB[128 * 256];   // Xin[site][k] bf16, swizzled
    __shared__ __align__(16) float Wt[128][8];       // tap weights per site
    __shared__ __align__(16) unsigned short Ot[128][8]; // tap site-indices (0..1727)
    __shared__ __align__(16) float a1L[64];
    __shared__ __align__(16) float b1L[64];

    const int n = blockIdx.x;
    const int kb = n >> 3, rb = n & 7;
    const int p = rb + 8 * (kb / 108);
    const int bx = kb % 108;
    const int zw = bx / 18, tw = bx % 18;
    const int yw = tw / 3, xwb = (tw % 3) * 2;
    const int tid = threadIdx.x;
    const int w = tid >> 6, l = tid & 63;

    if (tid < 64) { a1L[tid] = a1[p * 64 + tid]; b1L[tid] = b1[p * 64 + tid]; }

    // ---- build per-site tap tables ----
    if (tid < 128) {
        const int site = tid;
        const int wh = site >> 6, widx = site & 63;
        const int zl = widx >> 4, yl = (widx >> 2) & 3, xl = widx & 3;
        int iz0, iz1, iy0, iy1, ix0, ix1; float wz, wy, wx;
        interp_idx(zw * 4 + zl, iz0, iz1, wz);
        interp_idx(yw * 4 + yl, iy0, iy1, wy);
        interp_idx((xwb + wh) * 4 + xl, ix0, ix1, wx);
        float wz0 = 1.f - wz, wy0 = 1.f - wy, wx0 = 1.f - wx;
        Wt[site][0] = wz0*wy0*wx0; Wt[site][1] = wz0*wy0*wx;
        Wt[site][2] = wz0*wy*wx0;  Wt[site][3] = wz0*wy*wx;
        Wt[site][4] = wz*wy0*wx0;  Wt[site][5] = wz*wy0*wx;
        Wt[site][6] = wz*wy*wx0;   Wt[site][7] = wz*wy*wx;
        Ot[site][0] = (unsigned short)(iz0*144 + iy0*12 + ix0);
        Ot[site][1] = (unsigned short)(iz0*144 + iy0*12 + ix1);
        Ot[site][2] = (unsigned short)(iz0*144 + iy1*12 + ix0);
        Ot[site][3] = (unsigned short)(iz0*144 + iy1*12 + ix1);
        Ot[site][4] = (unsigned short)(iz1*144 + iy0*12 + ix0);
        Ot[site][5] = (unsigned short)(iz1*144 + iy0*12 + ix1);
        Ot[site][6] = (unsigned short)(iz1*144 + iy1*12 + ix0);
        Ot[site][7] = (unsigned short)(iz1*144 + iy1*12 + ix1);
    }

    const int bidx = props[p * 7 + 0];
    const int z2 = props[p * 7 + 1] >> 1;
    const int y2 = props[p * 7 + 2] >> 1;
    const int x2 = props[p * 7 + 3] >> 1;
    const unsigned short* y4sp = y4s + (long)p * 110592;

    // ---- Phase-B A-fragments (weights) from global, bf16 ----
    const int g = l >> 4;
    const int o2a = (w << 4) + (l & 15);
    bf16x8 afr[4];
    #pragma unroll
    for (int kk = 0; kk < 4; ++kk) {
        const float* wp = w_b2 + o2a * 128 + kk * 32 + g * 8;
        #pragma unroll
        for (int j = 0; j < 8; ++j) afr[kk][j] = (short)f2bf(wp[j]);
    }
    float bb[4];
    #pragma unroll
    for (int j = 0; j < 4; ++j) bb[j] = b_b2[(w << 4) + g * 4 + j];

    __syncthreads();   // tables + a1L/b1L ready

    // ================= Phase A1: x1, channel-major, register-batched taps =================
    {
        const int chq = l & 15;           // channel quad: c0 = chq*4 (8B per row)
        const int ssub = l >> 4;          // 0..3
        const unsigned short* base = y4sp + chq * 4;
        const float4 av = *(const float4*)&a1L[chq * 4];
        const float4 bv = *(const float4*)&b1L[chq * 4];
        #pragma unroll
        for (int it = 0; it < 8; ++it) {
            const int site = it * 16 + w * 4 + ssub;
            const float4 w0 = *(const float4*)&Wt[site][0];
            const float4 w1 = *(const float4*)&Wt[site][4];
            const u16x8 ov = *(const u16x8*)&Ot[site][0];
            float wt8[8] = { w0.x, w0.y, w0.z, w0.w, w1.x, w1.y, w1.z, w1.w };
            uint2 tv[8];
            #pragma unroll
            for (int t = 0; t < 8; ++t)
                tv[t] = *(const uint2*)(base + (int)ov[t] * 64);
            float u0 = 0.f, u1 = 0.f, u2 = 0.f, u3 = 0.f;
            #pragma unroll
            for (int t = 0; t < 8; ++t) {
                float wt = wt8[t];
                u0 += wt * bflo(tv[t].x); u1 += wt * bfhi(tv[t].x);
                u2 += wt * bflo(tv[t].y); u3 += wt * bfhi(tv[t].y);
            }
            float r0 = fmaxf(av.x * u0 + bv.x, 0.0f);
            float r1 = fmaxf(av.y * u1 + bv.y, 0.0f);
            float r2 = fmaxf(av.z * u2 + bv.z, 0.0f);
            float r3 = fmaxf(av.w * u3 + bv.w, 0.0f);
            unsigned lo = cvt_pk_bf16(r0, r1);
            unsigned hi = cvt_pk_bf16(r2, r3);
            *(uint2*)(XinB + (site << 8) + ((chq * 8) ^ swz(site))) = make_uint2(lo, hi);
        }
    }

    // ================= Phase A2: out1 crop =================
    {
        const int rq = tid & 31, cg = tid >> 5;   // cg: channels cg*8..+8
        const int wh = rq >> 4, zl = (rq >> 2) & 3, yl = rq & 3;
        const int zg = zw * 4 + zl, yg = yw * 4 + yl, xg0 = (xwb + wh) * 4;
        const float* o1p = out1 + ((long)bidx * 64 + cg * 8) * 262144
                         + (long)(z2 + zg) * 4096 + (y2 + yg) * 64 + (x2 + xg0);
        float vx[8][4];
        #pragma unroll
        for (int c = 0; c < 8; ++c) {
            float2 va = *(const float2*)(o1p + (long)c * 262144);
            float2 vb = *(const float2*)(o1p + (long)c * 262144 + 2);
            vx[c][0] = va.x; vx[c][1] = va.y; vx[c][2] = vb.x; vx[c][3] = vb.y;
        }
        #pragma unroll
        for (int xl = 0; xl < 4; ++xl) {
            int site = wh * 64 + zl * 16 + yl * 4 + xl;
            unsigned pk[4];
            #pragma unroll
            for (int j = 0; j < 4; ++j)
                pk[j] = cvt_pk_bf16(vx[2*j][xl], vx[2*j+1][xl]);
            *(uint4*)(XinB + (site << 8) + ((128 + cg * 16) ^ swz(site))) = make_uint4(pk[0], pk[1], pk[2], pk[3]);
        }
    }
    __syncthreads();

    // ================= Phase B: MFMA over 8 site-tiles =================
    float lS[4] = {0,0,0,0}, lQ[4] = {0,0,0,0};
    float vmx[2][4], vmn[2][4];
    #pragma unroll
    for (int q = 0; q < 4; ++q) {
        vmx[0][q] = vmx[1][q] = -3.402823466e38f;
        vmn[0][q] = vmn[1][q] =  3.402823466e38f;
    }

    #pragma unroll
    for (int st = 0; st < 8; ++st) {
        const int srow = st * 16 + (l & 15);
        const int sOff = srow << 8;
        const int ssw = swz(srow);
        bf16x8 bfr[4];
        #pragma unroll
        for (int kk = 0; kk < 4; ++kk) {
            int kbyte = kk * 64 + g * 16;
            bfr[kk] = *(const bf16x8*)(XinB + sOff + (kbyte ^ ssw));
        }
        f32x4 acc = {0.f, 0.f, 0.f, 0.f};
        #pragma unroll
        for (int kk = 0; kk < 4; ++kk)
            acc = __builtin_amdgcn_mfma_f32_16x16x32_bf16(afr[kk], bfr[kk], acc, 0, 0, 0);

        const int wh = st >> 2;
        #pragma unroll
        for (int j = 0; j < 4; ++j) {
            float v = acc[j] + bb[j];
            lS[j] += v; lQ[j] += v * v;
            vmx[wh][j] = fmaxf(vmx[wh][j], v);
            vmn[wh][j] = fminf(vmn[wh][j], v);
        }
    }

    // window reduce across the 16 site-columns
    #pragma unroll
    for (int wh = 0; wh < 2; ++wh)
        #pragma unroll
        for (int j = 0; j < 4; ++j) {
            float mx = vmx[wh][j], mn = vmn[wh][j];
            #pragma unroll
            for (int m = 1; m <= 8; m <<= 1) {
                mx = fmaxf(mx, __shfl_xor(mx, m));
                mn = fminf(mn, __shfl_xor(mn, m));
            }
            vmx[wh][j] = mx; vmn[wh][j] = mn;
        }
    if ((l & 15) == 0) {
        #pragma unroll
        for (int wh = 0; wh < 2; ++wh) {
            int win = tw * 2 + wh;
            #pragma unroll
            for (int j = 0; j < 4; ++j) {
                int o2d = (w << 4) + g * 4 + j;
                long idx = ((long)(p * 64 + o2d) * 6 + zw) * 36 + win;
                wmaxg[idx] = vmx[wh][j];
                wming[idx] = vmn[wh][j];
            }
        }
    }

    // ---- stats reduction across the 16 site-columns, then atomics ----
    #pragma unroll
    for (int j = 0; j < 4; ++j) {
        #pragma unroll
        for (int m = 1; m <= 8; m <<= 1) {
            lS[j] += __shfl_xor(lS[j], m);
            lQ[j] += __shfl_xor(lQ[j], m);
        }
    }
    if ((l & 15) == 0) {
        #pragma unroll
        for (int j = 0; j < 4; ++j) {
            int o2d = (w << 4) + g * 4 + j;
            atomicAdd(&s2sum[p * 64 + o2d], lS[j]);
            atomicAdd(&s2sq [p * 64 + o2d], lQ[j]);
        }
    }
}

// K4: finalize: apply stage-2 IN affine to window max (or min if negative scale), relu, write.
__global__ __launch_bounds__(256) void k4_final(
    const float* __restrict__ s2sum, const float* __restrict__ s2sq,
    const float* __restrict__ g_b2, const float* __restrict__ bt_b2,
    const float* __restrict__ wmaxg, const float* __restrict__ wming,
    float* __restrict__ outp)
{
    const int p = blockIdx.x;
    for (int idx = threadIdx.x; idx < 64 * 216; idx += 256) {
        int o2 = idx / 216, win = idx % 216;
        float s = s2sum[p * 64 + o2], q = s2sq[p * 64 + o2];
        float mean = s / 13824.0f;
        float var  = fmaxf(q / 13824.0f - mean * mean, 0.0f);
        float r = rsqrtf(var + EPSV);
        float sc = g_b2[o2] * r;
        float tb = bt_b2[o2] - mean * sc;
        long fi = (long)(p * 64 + o2) * 216 + win;
        float v = (sc >= 0.f) ? sc * wmaxg[fi] + tb : sc * wming[fi] + tb;
        outp[fi] = fmaxf(v, 0.0f);
    }
}

extern "C" void kernel_launch(void* const* d_in, const int* in_sizes, int n_in,
                              void* d_out, int out_size, void* d_ws, size_t ws_size,
                              hipStream_t stream)
{
    const float* out1  = (const float*)d_in[1];
    const float* comb2 = (const float*)d_in[2];
    const int*   props = (const int*)d_in[4];
    const float* w_up  = (const float*)d_in[5];
    const float* b_up  = (const float*)d_in[6];
    const float* g_up  = (const float*)d_in[7];
    const float* bt_up = (const float*)d_in[8];
    const float* w_b2  = (const float*)d_in[9];
    const float* b_b2  = (const float*)d_in[10];
    const float* g_b2  = (const float*)d_in[11];
    const float* bt_b2 = (const float*)d_in[12];
    float* outp = (float*)d_out;

    unsigned short* y4s = (unsigned short*)d_ws;   // 7,077,888 bf16 (site-major, 14.2 MB)
    float* fbase = (float*)(y4s + 7077888);
    float* a1    = fbase;                   // 4096
    float* b1    = a1 + 4096;               // 4096
    float* s2sum = b1 + 4096;               // 4096 (zeroed each call)
    float* s2sq  = s2sum + 4096;            // 4096 (zeroed each call)
    float* wmaxg = s2sq + 4096;             // 884,736
    float* wming = wmaxg + 884736;          // 884,736
    // total ~21.4 MiB

    hipMemsetAsync(s2sum, 0, 2 * 4096 * sizeof(float), stream);

    k1_conv1<<<768, 256, 0, stream>>>(comb2, props, w_up, b_up, y4s);
    k2_stats1<<<4096, 256, 0, stream>>>(y4s, g_up, bt_up, a1, b1);
    k3_conv2<<<6912, 256, 0, stream>>>(y4s, out1, props, a1, b1, w_b2, b_b2,
                                       s2sum, s2sq, wmaxg, wming);
    k4_final<<<NPROP, 256, 0, stream>>>(s2sum, s2sq, g_b2, bt_b2, wmaxg, wming, outp);
}